// Round 1
// baseline (260.468 us; speedup 1.0000x reference)
//
#include <hip/hip_runtime.h>

// SSIM, fully fused single pass + finalize.
// x,y: [16,3,512,512] f32; window: [3,1,11,11] f32 (separable Gaussian).
// Output: scalar mean SSIM (f32).
//
// Separable conv: conv2d(img, outer(g,g)) == vert1d(horiz1d(img, g), g),
// exact under zero padding. g recovered from window row 5:
//   w2d[5][k] = g[5]*g[k], w2d[5][5] = g[5]^2  ->  g[k] = w[55+k]/sqrt(w[55]).

#define IMG_H 512
#define IMG_W 512
#define NC    48            // 16 batches * 3 channels

constexpr int TW = 64;      // output tile width
constexpr int TH = 16;      // output tile height
constexpr int RW = TW + 10; // 74  staged region width
constexpr int RH = TH + 10; // 26  staged region height
constexpr int XS = 77;      // LDS stride for staged x/y (odd: bank-decorrelates rows)
constexpr int HS = 65;      // LDS stride for horizontal-conv rows (odd)

__global__ __launch_bounds__(256)
void ssim_fused(const float* __restrict__ x, const float* __restrict__ y,
                const float* __restrict__ w, double* __restrict__ out_acc)
{
    __shared__ float sx[RH][XS];
    __shared__ float sy[RH][XS];
    __shared__ float hh[5][RH][HS];   // hx, hy, hxx, hyy, hxy
    __shared__ float wsum[4];

    const int tid = threadIdx.x;
    const int x0 = blockIdx.x * TW - 5;
    const int y0 = blockIdx.y * TH - 5;
    const float* __restrict__ xp = x + (size_t)blockIdx.z * (IMG_H * IMG_W);
    const float* __restrict__ yp = y + (size_t)blockIdx.z * (IMG_H * IMG_W);

    // 1D gaussian from window (channel 0, row 5). Broadcast loads, L2-cached.
    float g[11];
    {
        const float g5inv = 1.0f / sqrtf(w[55 + 5]);
        #pragma unroll
        for (int k = 0; k < 11; ++k) g[k] = w[55 + k] * g5inv;
    }

    // ---- Phase 1: stage x,y halo region into LDS (zero OOB = zero padding)
    for (int i = tid; i < RH * RW; i += 256) {
        const int r = i / RW;
        const int c = i - r * RW;
        const int gr = y0 + r, gc = x0 + c;
        const bool ok = (gr >= 0) & (gr < IMG_H) & (gc >= 0) & (gc < IMG_W);
        const size_t idx = (size_t)gr * IMG_W + gc;
        sx[r][c] = ok ? xp[idx] : 0.0f;
        sy[r][c] = ok ? yp[idx] : 0.0f;
    }
    __syncthreads();

    // ---- Phase 2: horizontal 11-tap conv of {x,y,xx,yy,xy}; 4-col register blocking
    for (int t = tid; t < RH * (TW / 4); t += 256) {
        const int r  = t >> 4;          // / (TW/4)=16
        const int c0 = (t & 15) << 2;   // 0,4,...,60
        float xv[14], yv[14], xxv[14], yyv[14], xyv[14];
        #pragma unroll
        for (int k = 0; k < 14; ++k) {
            const float a = sx[r][c0 + k];
            const float b = sy[r][c0 + k];
            xv[k] = a; yv[k] = b;
            xxv[k] = a * a; yyv[k] = b * b; xyv[k] = a * b;
        }
        #pragma unroll
        for (int j = 0; j < 4; ++j) {
            float s0 = 0.f, s1 = 0.f, s2 = 0.f, s3 = 0.f, s4 = 0.f;
            #pragma unroll
            for (int k = 0; k < 11; ++k) {
                const float gk = g[k];
                s0 = fmaf(gk, xv[j + k], s0);
                s1 = fmaf(gk, yv[j + k], s1);
                s2 = fmaf(gk, xxv[j + k], s2);
                s3 = fmaf(gk, yyv[j + k], s3);
                s4 = fmaf(gk, xyv[j + k], s4);
            }
            hh[0][r][c0 + j] = s0;
            hh[1][r][c0 + j] = s1;
            hh[2][r][c0 + j] = s2;
            hh[3][r][c0 + j] = s3;
            hh[4][r][c0 + j] = s4;
        }
    }
    __syncthreads();

    // ---- Phase 3: vertical 11-tap conv + SSIM; 4-row register blocking
    const int c  = tid & 63;
    const int r0 = (tid >> 6) << 2;     // 0,4,8,12
    float a0[14], a1[14], a2[14], a3[14], a4[14];
    #pragma unroll
    for (int k = 0; k < 14; ++k) {
        a0[k] = hh[0][r0 + k][c];
        a1[k] = hh[1][r0 + k][c];
        a2[k] = hh[2][r0 + k][c];
        a3[k] = hh[3][r0 + k][c];
        a4[k] = hh[4][r0 + k][c];
    }

    const float C1 = 1e-4f;   // 0.01^2
    const float C2 = 9e-4f;   // 0.03^2
    float local = 0.0f;
    #pragma unroll
    for (int j = 0; j < 4; ++j) {
        float m1 = 0.f, m2 = 0.f, cxx = 0.f, cyy = 0.f, cxy = 0.f;
        #pragma unroll
        for (int k = 0; k < 11; ++k) {
            const float gk = g[k];
            m1  = fmaf(gk, a0[j + k], m1);
            m2  = fmaf(gk, a1[j + k], m2);
            cxx = fmaf(gk, a2[j + k], cxx);
            cyy = fmaf(gk, a3[j + k], cyy);
            cxy = fmaf(gk, a4[j + k], cxy);
        }
        const float m1s = m1 * m1, m2s = m2 * m2, m12 = m1 * m2;
        const float v1  = cxx - m1s;          // sigma1_sq
        const float v2  = cyy - m2s;          // sigma2_sq
        const float v12 = cxy - m12;          // sigma12
        const float num = (2.0f * m12 + C1) * (2.0f * v12 + C2);
        const float den = (m1s + m2s + C1) * (v1 + v2 + C2);
        local += num / den;
    }

    // ---- Block reduction: wave shuffle -> LDS -> one f64 atomic per block
    #pragma unroll
    for (int off = 32; off > 0; off >>= 1)
        local += __shfl_down(local, off, 64);
    if ((tid & 63) == 0) wsum[tid >> 6] = local;
    __syncthreads();
    if (tid == 0) {
        const double blk = (double)wsum[0] + (double)wsum[1]
                         + (double)wsum[2] + (double)wsum[3];
        atomicAdd(out_acc, blk);
    }
}

__global__ void ssim_finalize(const double* __restrict__ acc, float* __restrict__ out)
{
    out[0] = (float)(acc[0] / (double)((size_t)NC * IMG_H * IMG_W));
}

extern "C" void kernel_launch(void* const* d_in, const int* in_sizes, int n_in,
                              void* d_out, int out_size, void* d_ws, size_t ws_size,
                              hipStream_t stream)
{
    const float* x = (const float*)d_in[0];
    const float* y = (const float*)d_in[1];
    const float* w = (const float*)d_in[2];
    double* acc = (double*)d_ws;

    hipMemsetAsync(d_ws, 0, sizeof(double), stream);

    dim3 grid(IMG_W / TW, IMG_H / TH, NC);   // (8, 32, 48) = 12288 blocks
    ssim_fused<<<grid, 256, 0, stream>>>(x, y, w, acc);
    ssim_finalize<<<1, 1, 0, stream>>>(acc, (float*)d_out);
}

// Round 2
// 225.632 us; speedup vs baseline: 1.1544x; 1.1544x over previous
//
#include <hip/hip_runtime.h>

// SSIM, fused separable-conv single pass + reduce.
// x,y: [16,3,512,512] f32; window: [3,1,11,11] f32 (separable Gaussian).
// Output: scalar mean SSIM (f32).
//
// Vertical conv FIRST (intermediate is TH x (TW+10), smaller than
// horizontal-first's (TH+10) x TW): LDS 40.6 KB -> 4 blocks/CU.
// Phase-H LDS reads vectorized to ds_read_b128: vv is column-shifted by 2
// (vv[c] = vconv at staged col c+2) so each output-quad's 14-tap window
// [j0+1 .. j0+14] sits inside the aligned 16-float span [j0 .. j0+16).

#define IMG_H 512
#define IMG_W 512
#define NC    48            // 16 batches * 3 channels

constexpr int TW = 64;      // output tile width
constexpr int TH = 16;      // output tile height
constexpr int SW = 78;      // staged cols: image 64bx-8 .. 64bx+69 (need -5..+68)
constexpr int SH = 26;      // staged rows: image 16by-5 .. 16by+20
constexpr int SS = 78;      // staged LDS stride (words)
constexpr int VW = 76;      // vv stride (multiple of 4 for b128 alignment)
constexpr int NBLK = (IMG_W / TW) * (IMG_H / TH) * NC;   // 12288

__global__ __launch_bounds__(256, 4)
void ssim_fused(const float* __restrict__ x, const float* __restrict__ y,
                const float* __restrict__ w, double* __restrict__ part,
                int use_atomic)
{
    __shared__ __align__(16) float sx[SH][SS];
    __shared__ __align__(16) float sy[SH][SS];
    __shared__ __align__(16) float vv[5][TH][VW];  // vmu1, vmu2, vxx, vyy, vxy
    __shared__ float wsum[4];

    const int tid = threadIdx.x;
    const int x0 = blockIdx.x * TW - 8;    // staged col 0 (mult of 4 vs image)
    const int y0 = blockIdx.y * TH - 5;    // staged row 0
    const float* __restrict__ xp = x + (size_t)blockIdx.z * (IMG_H * IMG_W);
    const float* __restrict__ yp = y + (size_t)blockIdx.z * (IMG_H * IMG_W);

    // 1D gaussian from window row 5: w2d[5][k] = g5*g[k], g[k] = w[55+k]/sqrt(w[60]).
    float g[11];
    {
        const float g5inv = 1.0f / sqrtf(w[55 + 5]);
        #pragma unroll
        for (int k = 0; k < 11; ++k) g[k] = w[55 + k] * g5inv;
    }

    // ---- Phase 1: stage x,y halo region into LDS (zero OOB = zero padding)
    for (int i = tid; i < SH * SW; i += 256) {
        const int r = i / SW;
        const int c = i - r * SW;
        const int gr = y0 + r, gc = x0 + c;
        const bool ok = (gr >= 0) & (gr < IMG_H) & (gc >= 0) & (gc < IMG_W);
        const size_t idx = (size_t)gr * IMG_W + gc;
        sx[r][c] = ok ? xp[idx] : 0.0f;
        sy[r][c] = ok ? yp[idx] : 0.0f;
    }
    __syncthreads();

    // ---- Phase V: vertical 11-tap conv of {x,y,xx,yy,xy} at staged col c+2,
    //      4-row register blocking. vv cols 0..74 (col 75 left unwritten).
    for (int t = tid; t < 75 * 4; t += 256) {
        const int c  = t % 75;
        const int r0 = (t / 75) << 2;
        float xv[14], yv[14], xxv[14], yyv[14], xyv[14];
        #pragma unroll
        for (int k = 0; k < 14; ++k) {
            const float a = sx[r0 + k][c + 2];
            const float b = sy[r0 + k][c + 2];
            xv[k] = a; yv[k] = b;
            xxv[k] = a * a; yyv[k] = b * b; xyv[k] = a * b;
        }
        #pragma unroll
        for (int j = 0; j < 4; ++j) {
            float s0 = 0.f, s1 = 0.f, s2 = 0.f, s3 = 0.f, s4 = 0.f;
            #pragma unroll
            for (int k = 0; k < 11; ++k) {
                const float gk = g[k];
                s0 = fmaf(gk, xv[j + k],  s0);
                s1 = fmaf(gk, yv[j + k],  s1);
                s2 = fmaf(gk, xxv[j + k], s2);
                s3 = fmaf(gk, yyv[j + k], s3);
                s4 = fmaf(gk, xyv[j + k], s4);
            }
            vv[0][r0 + j][c] = s0;
            vv[1][r0 + j][c] = s1;
            vv[2][r0 + j][c] = s2;
            vv[3][r0 + j][c] = s3;
            vv[4][r0 + j][c] = s4;
        }
    }
    __syncthreads();

    // ---- Phase H: horizontal 11-tap conv + SSIM. Thread -> (row, 4-col group).
    // Output col j (image 64bx+j) taps vv[r][j+1 .. j+11]; quad j0 needs
    // vv[j0+1 .. j0+14] subset of aligned [j0 .. j0+16) -> 4x ds_read_b128 per q.
    const int r  = tid >> 4;            // 0..15
    const int j0 = (tid & 15) << 2;     // 0,4,...,60

    float acc[5][4];
    #pragma unroll
    for (int q = 0; q < 5; ++q) {
        const float4* vp = (const float4*)(&vv[q][r][j0]);
        const float4 A = vp[0], B = vp[1], C = vp[2], D = vp[3];
        const float win[16] = {A.x, A.y, A.z, A.w, B.x, B.y, B.z, B.w,
                               C.x, C.y, C.z, C.w, D.x, D.y, D.z, D.w};
        #pragma unroll
        for (int t = 0; t < 4; ++t) {
            float s = 0.f;
            #pragma unroll
            for (int k = 0; k < 11; ++k) s = fmaf(g[k], win[t + 1 + k], s);
            acc[q][t] = s;
        }
    }

    const float C1 = 1e-4f;   // 0.01^2
    const float C2 = 9e-4f;   // 0.03^2
    float local = 0.0f;
    #pragma unroll
    for (int t = 0; t < 4; ++t) {
        const float m1 = acc[0][t], m2 = acc[1][t];
        const float m1s = m1 * m1, m2s = m2 * m2, m12 = m1 * m2;
        const float v1  = acc[2][t] - m1s;
        const float v2  = acc[3][t] - m2s;
        const float v12 = acc[4][t] - m12;
        const float num = (2.0f * m12 + C1) * (2.0f * v12 + C2);
        const float den = (m1s + m2s + C1) * (v1 + v2 + C2);
        local += num / den;
    }

    // ---- Block reduction: wave shuffle -> LDS -> one store (or atomic) per block
    #pragma unroll
    for (int off = 32; off > 0; off >>= 1)
        local += __shfl_down(local, off, 64);
    if ((tid & 63) == 0) wsum[tid >> 6] = local;
    __syncthreads();
    if (tid == 0) {
        const double blk = (double)wsum[0] + (double)wsum[1]
                         + (double)wsum[2] + (double)wsum[3];
        if (use_atomic) {
            atomicAdd(part, blk);
        } else {
            const int bflat = blockIdx.x
                            + gridDim.x * (blockIdx.y + gridDim.y * blockIdx.z);
            part[bflat] = blk;
        }
    }
}

__global__ void ssim_reduce(const double* __restrict__ part, float* __restrict__ out,
                            int n)
{
    __shared__ double s[256];
    double t = 0.0;
    for (int i = threadIdx.x; i < n; i += 256) t += part[i];
    s[threadIdx.x] = t;
    __syncthreads();
    for (int off = 128; off > 0; off >>= 1) {
        if (threadIdx.x < off) s[threadIdx.x] += s[threadIdx.x + off];
        __syncthreads();
    }
    if (threadIdx.x == 0)
        out[0] = (float)(s[0] / (double)((size_t)NC * IMG_H * IMG_W));
}

extern "C" void kernel_launch(void* const* d_in, const int* in_sizes, int n_in,
                              void* d_out, int out_size, void* d_ws, size_t ws_size,
                              hipStream_t stream)
{
    const float* x = (const float*)d_in[0];
    const float* y = (const float*)d_in[1];
    const float* w = (const float*)d_in[2];
    double* part = (double*)d_ws;

    const bool fits = ws_size >= (size_t)NBLK * sizeof(double);
    dim3 grid(IMG_W / TW, IMG_H / TH, NC);   // (8, 32, 48) = 12288 blocks

    if (fits) {
        // every block writes its own slot; no memset, no atomics
        ssim_fused<<<grid, 256, 0, stream>>>(x, y, w, part, 0);
        ssim_reduce<<<1, 256, 0, stream>>>(part, (float*)d_out, NBLK);
    } else {
        hipMemsetAsync(d_ws, 0, sizeof(double), stream);
        ssim_fused<<<grid, 256, 0, stream>>>(x, y, w, part, 1);
        ssim_reduce<<<1, 256, 0, stream>>>(part, (float*)d_out, 1);
    }
}